// Round 4
// baseline (1177.994 us; speedup 1.0000x reference)
//
#include <hip/hip_runtime.h>
#include <hip/hip_bf16.h>
#include <math.h>

#define B_    4
#define S_    2048
#define D_    1024
#define H_    8
#define N_    16
#define HN_   128
#define L_    2
#define DFF_  4096
#define C_    1024
#define MTOK  8192   // B_*S_

using bf16 = __hip_bfloat16;
typedef __attribute__((ext_vector_type(8))) short  short8;
typedef __attribute__((ext_vector_type(4))) float  f32x4;

static __device__ __forceinline__ float sigmoidf_(float x) { return 1.f / (1.f + expf(-x)); }

static __device__ __forceinline__ unsigned short f2bf_bits(float f) {
    bf16 h = __float2bfloat16(f);
    return __builtin_bit_cast(unsigned short, h);
}

#define GLOAD_LDS(gp, lp) \
    __builtin_amdgcn_global_load_lds((__attribute__((address_space(1))) void*)(gp), \
                                     (__attribute__((address_space(3))) void*)(lp), 16, 0, 0)

#define VMCNT(n) asm volatile("s_waitcnt vmcnt(" #n ")" ::: "memory")
#define BARRIER() do { asm volatile("" ::: "memory"); __builtin_amdgcn_s_barrier(); \
                       asm volatile("" ::: "memory"); } while (0)

// ---------------------------------------------------------------------------
// Weight transpose + convert: src f32 [K][N] -> dst bf16 rows (n*rstride+roff)
// dst row length K. rstride=2/roff=0,1 builds the w1/w3 row-interleaved fused
// weight; rstride=1/roff=0 is the plain [N][K] transpose.
// ---------------------------------------------------------------------------
__global__ __launch_bounds__(256) void transpose_k(const float* __restrict__ src,
                                                   bf16* __restrict__ dst,
                                                   int K, int N, int rstride, int roff) {
    __shared__ float t[32][33];
    int n0 = blockIdx.x * 32, k0 = blockIdx.y * 32;
    int tx = threadIdx.x, ty = threadIdx.y;
    #pragma unroll
    for (int i = ty; i < 32; i += 8)
        t[i][tx] = src[(size_t)(k0 + i) * N + n0 + tx];
    __syncthreads();
    #pragma unroll
    for (int i = ty; i < 32; i += 8)
        dst[((size_t)(n0 + i) * rstride + roff) * K + k0 + tx] = __float2bfloat16(t[tx][i]);
}

// ---------------------------------------------------------------------------
// Embedding
// ---------------------------------------------------------------------------
__global__ __launch_bounds__(256) void embed_k(const int* __restrict__ x,
                                               const float* __restrict__ emb,
                                               const float* __restrict__ pos,
                                               float* __restrict__ h) {
    int tok = blockIdx.x, t = threadIdx.x;
    int id = x[tok];
    int s  = tok & (S_ - 1);
    float4 a = ((const float4*)(emb + (size_t)id * D_))[t];
    float4 p = ((const float4*)(pos + (size_t)s * D_))[t];
    float4 r; r.x = a.x + p.x; r.y = a.y + p.y; r.z = a.z + p.z; r.w = a.w + p.w;
    ((float4*)(h + (size_t)tok * D_))[t] = r;
}

// ---------------------------------------------------------------------------
// LayerNorm (row=1024) -> bf16
// ---------------------------------------------------------------------------
__global__ __launch_bounds__(256) void ln_k(const float* __restrict__ x,
                                            const float* __restrict__ g,
                                            const float* __restrict__ be,
                                            bf16* __restrict__ out) {
    int row = blockIdx.x, t = threadIdx.x;
    float4 v = ((const float4*)(x + (size_t)row * D_))[t];
    float s  = v.x + v.y + v.z + v.w;
    float sq = v.x * v.x + v.y * v.y + v.z * v.z + v.w * v.w;
    #pragma unroll
    for (int o = 32; o > 0; o >>= 1) {
        s  += __shfl_down(s, o);
        sq += __shfl_down(sq, o);
    }
    __shared__ float red[8];
    __shared__ float mv[2];
    int wave = t >> 6, lane = t & 63;
    if (lane == 0) { red[wave] = s; red[4 + wave] = sq; }
    __syncthreads();
    if (t == 0) {
        float S0 = red[0] + red[1] + red[2] + red[3];
        float Q  = red[4] + red[5] + red[6] + red[7];
        float m  = S0 * (1.f / 1024.f);
        float var = Q * (1.f / 1024.f) - m * m;
        mv[0] = m; mv[1] = rsqrtf(var + 1e-5f);
    }
    __syncthreads();
    float m = mv[0], rs = mv[1];
    float4 gg = ((const float4*)g)[t];
    float4 bb = ((const float4*)be)[t];
    ushort4 o;
    o.x = f2bf_bits((v.x - m) * rs * gg.x + bb.x);
    o.y = f2bf_bits((v.y - m) * rs * gg.y + bb.y);
    o.z = f2bf_bits((v.z - m) * rs * gg.z + bb.z);
    o.w = f2bf_bits((v.w - m) * rs * gg.w + bb.w);
    ((ushort4*)(out + (size_t)row * D_))[t] = o;
}

// ---------------------------------------------------------------------------
// SSM scan
// ---------------------------------------------------------------------------
__global__ __launch_bounds__(256) void ssm_scan_k(const float* __restrict__ ab,
                                                  bf16* __restrict__ hs) {
    const int CL = S_ / 16;
    int bh = blockIdx.x;
    int b = bh >> 3, hh = bh & 7;
    int t = threadIdx.x;
    int chunk = t >> 4, n = t & 15;
    size_t rowbase = (size_t)b * S_ + (size_t)chunk * CL;
    const float* ap = ab + rowbase * 256 + hh * 16 + n;
    const float* bp = ap + 128;

    float A = 1.f, Bc = 0.f;
    for (int i = 0; i < CL; i++) {
        float a = ap[(size_t)i * 256], bv = bp[(size_t)i * 256];
        A *= a; Bc = a * Bc + bv;
    }
    __shared__ float sA[16][16], sB[16][16], sH[16][16];
    sA[chunk][n] = A; sB[chunk][n] = Bc;
    __syncthreads();
    if (t < 16) {
        float run = 0.f;
        #pragma unroll
        for (int c = 0; c < 16; c++) {
            sH[c][t] = run;
            run = sA[c][t] * run + sB[c][t];
        }
    }
    __syncthreads();
    float hrun = sH[chunk][n];
    bf16* op = hs + rowbase * 128 + hh * 16 + n;
    for (int i = 0; i < CL; i++) {
        float a = ap[(size_t)i * 256], bv = bp[(size_t)i * 256];
        hrun = a * hrun + bv;
        op[(size_t)i * 128] = __float2bfloat16(hrun);
    }
}

// ---------------------------------------------------------------------------
// Epilogue element-ops
// ---------------------------------------------------------------------------
enum { EP_AB = 0, EP_BIAS_RES = 1, EP_BIAS_BF16 = 2, EP_SILUMUL_BF16 = 3,
       EP_GELU_BF16 = 4, EP_BIAS_F32 = 5, EP_W13 = 6 };

template <int EP>
static __device__ __forceinline__ void ep_store(
    float v, size_t idx, int col,
    float* __restrict__ outF, bf16* __restrict__ outB,
    const float* __restrict__ b1, const float* __restrict__ b2,
    const float* __restrict__ resF, const bf16* __restrict__ resB) {
    if constexpr (EP == EP_AB) {
        if (col < HN_) v = sigmoidf_(v + b1[col]);
        else           v = v + b2[col - HN_];
        outF[idx] = v;
    } else if constexpr (EP == EP_BIAS_RES) {
        outF[idx] = v + b1[col] + resF[idx];
    } else if constexpr (EP == EP_BIAS_BF16) {
        outB[idx] = __float2bfloat16(v + b1[col]);
    } else if constexpr (EP == EP_SILUMUL_BF16) {
        float c1 = __bfloat162float(resB[idx]);
        float sil = c1 * sigmoidf_(c1);
        outB[idx] = __float2bfloat16((v + b1[col]) * sil);
    } else if constexpr (EP == EP_GELU_BF16) {
        float xv = v + b1[col];
        outB[idx] = __float2bfloat16(0.5f * xv * (1.f + erff(xv * 0.70710678118f)));
    } else {  // EP_BIAS_F32
        outF[idx] = v + b1[col];
    }
}

// ---------------------------------------------------------------------------
// 128x128 GEMM (m97 structure) — kept for small-N GEMMs (ab, out-proj)
// ---------------------------------------------------------------------------
template <int EP>
__global__ __launch_bounds__(256) void gemm_k(
    const bf16* __restrict__ A, const bf16* __restrict__ W,
    float* __restrict__ outF, bf16* __restrict__ outB,
    const float* __restrict__ b1, const float* __restrict__ b2,
    const float* __restrict__ resF, const bf16* __restrict__ resB,
    int M, int N, int K) {
    __shared__ __align__(16) bf16 As[128 * 64];
    __shared__ __align__(16) bf16 Bs[128 * 64];
    const int tid = threadIdx.x;
    const int wave = tid >> 6, lane = tid & 63;
    const int bm = blockIdx.x * 128, bn = blockIdx.y * 128;
    const int wr = (wave >> 1) * 64, wc = (wave & 1) * 64;

    f32x4 acc[4][4];
    #pragma unroll
    for (int m = 0; m < 4; m++)
        #pragma unroll
        for (int n = 0; n < 4; n++) acc[m][n] = f32x4{0.f, 0.f, 0.f, 0.f};

    const int srow = tid >> 3;
    const int skc  = (tid & 7) * 8;

    for (int k0 = 0; k0 < K; k0 += 64) {
        #pragma unroll
        for (int rr = 0; rr < 4; rr++) {
            int row = rr * 32 + srow;
            GLOAD_LDS(A + (size_t)(bm + row) * K + k0 + skc, As + row * 64 + skc);
            GLOAD_LDS(W + (size_t)(bn + row) * K + k0 + skc, Bs + row * 64 + skc);
        }
        __syncthreads();
        #pragma unroll
        for (int ks = 0; ks < 2; ks++) {
            const int kb = ks * 32 + (lane >> 4) * 8;
            short8 af[4], bfr[4];
            #pragma unroll
            for (int m = 0; m < 4; m++)
                af[m] = *reinterpret_cast<const short8*>(As + (wr + m * 16 + (lane & 15)) * 64 + kb);
            #pragma unroll
            for (int n = 0; n < 4; n++)
                bfr[n] = *reinterpret_cast<const short8*>(Bs + (wc + n * 16 + (lane & 15)) * 64 + kb);
            #pragma unroll
            for (int m = 0; m < 4; m++)
                #pragma unroll
                for (int n = 0; n < 4; n++)
                    acc[m][n] = __builtin_amdgcn_mfma_f32_16x16x32_bf16(af[m], bfr[n], acc[m][n], 0, 0, 0);
        }
        __syncthreads();
    }

    const int cb = bn + wc + (lane & 15);
    const int rb = bm + wr + (lane >> 4) * 4;
    #pragma unroll
    for (int m = 0; m < 4; m++)
        #pragma unroll
        for (int n = 0; n < 4; n++) {
            int col = cb + n * 16;
            #pragma unroll
            for (int i = 0; i < 4; i++) {
                int row = rb + m * 16 + i;
                ep_store<EP>(acc[m][n][i], (size_t)row * N + col, col,
                             outF, outB, b1, b2, resF, resB);
            }
        }
}

// ---------------------------------------------------------------------------
// 256xBN phase-split GEMM, round-4 revision:
//  * fragment reads pipelined one phase ahead (ds_read of phase p+1 issued
//    before phase p's MFMA cluster) -> DS pipe overlaps MFMA pipe
//  * all address arithmetic hoisted out of the K-loop
//  * EP_W13: fused w1|w3 row-interleaved weights; even col = w1, odd = w3;
//    shfl_xor(1) pairs g/u, even lanes store silu(g)*u to ld N/2
// LDS ledger & counted-vmcnt unchanged from round 3 (verified passing).
// ---------------------------------------------------------------------------
extern __shared__ __align__(16) char smem_g256[];

template <int BN, int EP>
__global__ __launch_bounds__(512, 2) void gemm256_k(
    const bf16* __restrict__ A, const bf16* __restrict__ W,
    float* __restrict__ outF, bf16* __restrict__ outB,
    const float* __restrict__ b1, const float* __restrict__ b2,
    const float* __restrict__ resF, const bf16* __restrict__ resB,
    int M, int N, int K) {
    constexpr int NR   = BN / 64;          // n-frags per wave (4 or 2)
    constexpr int NBJ  = BN / 64;          // B stage loads per thread
    constexpr int WCS  = NR * 16;          // per-wave column stride
    constexpr int ASZB = 256 * 64 * 2;     // A-tile bytes (32 KiB)
    constexpr int BSZB = BN * 64 * 2;
    constexpr int BUFB = ASZB + BSZB;

    const int tid = threadIdx.x;
    const int wid = tid >> 6, lane = tid & 63;
    const int wr = wid >> 2, wc = wid & 3;
    const int l15 = lane & 15, l4 = lane >> 4;

    // bijective XCD swizzle (gridDim.x % 8 == 0 for all launches)
    const int nwg = gridDim.x;
    const int bid = ((int)blockIdx.x & 7) * (nwg >> 3) + ((int)blockIdx.x >> 3);
    const int gx = M >> 8;
    const int bm = (bid % gx) * 256;
    const int bn = (bid / gx) * BN;

    const int nt = K >> 6;

    // ---- hoisted staging addresses ----
    const int tr   = tid >> 3;                       // 0..63 (row within 64-row j-chunk)
    const int cc8  = (((tid & 7) ^ (tr & 7)) << 3);  // pre-swizzled k-chunk (elements)
    const bf16* gA0 = A + (size_t)(bm + tr) * K + cc8;
    const bf16* gB0 = W + (size_t)(bn + tr) * K + cc8;
    const int ldsc = tid << 4;                       // byte offset of j=0 chunk

    auto stageA = [&](int t, int j) {
        GLOAD_LDS(gA0 + (size_t)j * ((size_t)K << 6) + ((size_t)t << 6),
                  smem_g256 + (size_t)(t & 1) * BUFB + ldsc + (j << 13));
    };
    auto stageB = [&](int t, int j) {
        GLOAD_LDS(gB0 + (size_t)j * ((size_t)K << 6) + ((size_t)t << 6),
                  smem_g256 + (size_t)(t & 1) * BUFB + ASZB + ldsc + (j << 13));
    };

    // ---- hoisted LDS read offsets ----
    const int swz   = (lane & 7) << 4;
    const int kof0  = ((l4 << 4)) ^ swz;
    const int kof1  = (64 + (l4 << 4)) ^ swz;
    const int rbaseA = (wr * 128 + l15) << 7;
    const int rbaseB = ASZB + ((wc * WCS + l15) << 7);

    auto rdA = [&](int bo, int m, int kof) -> short8 {
        return *reinterpret_cast<const short8*>(smem_g256 + bo + rbaseA + (m << 11) + kof);
    };
    auto rdB = [&](int bo, int n, int kof) -> short8 {
        return *reinterpret_cast<const short8*>(smem_g256 + bo + rbaseB + (n << 11) + kof);
    };

    f32x4 acc[8][NR];
    #pragma unroll
    for (int m = 0; m < 8; m++)
        #pragma unroll
        for (int n = 0; n < NR; n++) acc[m][n] = f32x4{0.f, 0.f, 0.f, 0.f};

    // prologue: tiles 0 and 1 fully staged
    #pragma unroll
    for (int j = 0; j < 4; j++) stageA(0, j);
    #pragma unroll
    for (int j = 0; j < NBJ; j++) stageB(0, j);
    #pragma unroll
    for (int j = 0; j < 4; j++) stageA(1, j);
    #pragma unroll
    for (int j = 0; j < NBJ; j++) stageB(1, j);

    short8 a0[4], a1[4], bF0[NR], bF1[NR];

    for (int v = 0; v < nt; ++v) {
        const int bo = (v & 1) * BUFB;
        if (v == 0)            { if constexpr (BN == 256) VMCNT(8); else VMCNT(6); }
        else if (v + 1 < nt)   { if constexpr (BN == 256) VMCNT(6); else VMCNT(4); }
        else                   VMCNT(0);
        BARRIER();   // tile v fully in LDS for every thread

        // ---- phase 0: reads for P0 (+ all B frags), stage A-late(v+1) ----
        #pragma unroll
        for (int m = 0; m < 4; m++) a0[m] = rdA(bo, m, kof0);
        #pragma unroll
        for (int n = 0; n < NR; n++) bF0[n] = rdB(bo, n, kof0);
        #pragma unroll
        for (int n = 0; n < NR; n++) bF1[n] = rdB(bo, n, kof1);
        if (v >= 1 && v + 1 < nt) { stageA(v + 1, 1); stageA(v + 1, 3); }
        BARRIER();
        #pragma unroll
        for (int m = 0; m < 4; m++) a1[m] = rdA(bo, m, kof1);   // prefetch P1
        __builtin_amdgcn_s_setprio(1);
        #pragma unroll
        for (int m = 0; m < 4; m++)
            #pragma unroll
            for (int n = 0; n < NR; n++)
                acc[m][n] = __builtin_amdgcn_mfma_f32_16x16x32_bf16(a0[m], bF0[n], acc[m][n], 0, 0, 0);
        __builtin_amdgcn_s_setprio(0);
        BARRIER();

        // ---- phase 1: MFMA(a1,bF1); prefetch P2's A frags ----
        #pragma unroll
        for (int m = 0; m < 4; m++) a0[m] = rdA(bo, 4 + m, kof0);
        __builtin_amdgcn_s_setprio(1);
        #pragma unroll
        for (int m = 0; m < 4; m++)
            #pragma unroll
            for (int n = 0; n < NR; n++)
                acc[m][n] = __builtin_amdgcn_mfma_f32_16x16x32_bf16(a1[m], bF1[n], acc[m][n], 0, 0, 0);
        __builtin_amdgcn_s_setprio(0);
        BARRIER();   // B-region + A-early rows of tile v fully consumed

        // ---- phase 2: stage tile v+2 (B + A-early); MFMA(a0,bF0); prefetch P3 ----
        if (v + 2 < nt) {
            #pragma unroll
            for (int j = 0; j < NBJ; j++) stageB(v + 2, j);
            stageA(v + 2, 0); stageA(v + 2, 2);
        }
        #pragma unroll
        for (int m = 0; m < 4; m++) a1[m] = rdA(bo, 4 + m, kof1);
        __builtin_amdgcn_s_setprio(1);
        #pragma unroll
        for (int m = 0; m < 4; m++)
            #pragma unroll
            for (int n = 0; n < NR; n++)
                acc[4 + m][n] = __builtin_amdgcn_mfma_f32_16x16x32_bf16(a0[m], bF0[n], acc[4 + m][n], 0, 0, 0);
        __builtin_amdgcn_s_setprio(0);
        BARRIER();

        // ---- phase 3: MFMA(a1,bF1) ----
        __builtin_amdgcn_s_setprio(1);
        #pragma unroll
        for (int m = 0; m < 4; m++)
            #pragma unroll
            for (int n = 0; n < NR; n++)
                acc[4 + m][n] = __builtin_amdgcn_mfma_f32_16x16x32_bf16(a1[m], bF1[n], acc[4 + m][n], 0, 0, 0);
        __builtin_amdgcn_s_setprio(0);
        BARRIER();
    }

    // ---- epilogue ----
    const int gc0 = bn + wc * WCS + l15;
    const int gr0 = bm + wr * 128 + l4 * 4;
    #pragma unroll
    for (int m = 0; m < 8; m++)
        #pragma unroll
        for (int n = 0; n < NR; n++) {
            int col = gc0 + n * 16;
            #pragma unroll
            for (int i = 0; i < 4; i++) {
                int row = gr0 + m * 16 + i;
                if constexpr (EP == EP_W13) {
                    float xv = acc[m][n][i] + ((col & 1) ? b2[col >> 1] : b1[col >> 1]);
                    float part = __shfl_xor(xv, 1);
                    if (!(col & 1)) {
                        float r = xv * sigmoidf_(xv) * part;   // silu(g) * u
                        outB[(size_t)row * (N >> 1) + (col >> 1)] = __float2bfloat16(r);
                    }
                } else {
                    ep_store<EP>(acc[m][n][i], (size_t)row * N + col, col,
                                 outF, outB, b1, b2, resF, resB);
                }
            }
        }
}

// ---------------------------------------------------------------------------
extern "C" void kernel_launch(void* const* d_in, const int* in_sizes, int n_in,
                              void* d_out, int out_size, void* d_ws, size_t ws_size,
                              hipStream_t stream) {
    const int*   x       = (const int*)  d_in[0];
    const float* emb     = (const float*)d_in[1];
    const float* pos_emb = (const float*)d_in[2];
    const float* alpha_W = (const float*)d_in[3];
    const float* alpha_b = (const float*)d_in[4];
    const float* in_W    = (const float*)d_in[5];
    const float* in_b    = (const float*)d_in[6];
    const float* out_W   = (const float*)d_in[7];
    const float* out_b   = (const float*)d_in[8];
    const float* ssm_g   = (const float*)d_in[9];
    const float* ssm_be  = (const float*)d_in[10];
    const float* w1_W    = (const float*)d_in[11];
    const float* w1_b    = (const float*)d_in[12];
    const float* w2_W    = (const float*)d_in[13];
    const float* w2_b    = (const float*)d_in[14];
    const float* w3_W    = (const float*)d_in[15];
    const float* w3_b    = (const float*)d_in[16];
    const float* ff_g    = (const float*)d_in[17];
    const float* ff_be   = (const float*)d_in[18];
    const float* on_g    = (const float*)d_in[19];
    const float* on_be   = (const float*)d_in[20];
    const float* h1_W    = (const float*)d_in[21];
    const float* h1_b    = (const float*)d_in[22];
    const float* h2_W    = (const float*)d_in[23];
    const float* h2_b    = (const float*)d_in[24];
    float* outp = (float*)d_out;
    (void)in_sizes; (void)n_in; (void)out_size; (void)ws_size;

    hipFuncSetAttribute((const void*)gemm256_k<256, EP_W13>,       hipFuncAttributeMaxDynamicSharedMemorySize, 131072);
    hipFuncSetAttribute((const void*)gemm256_k<256, EP_GELU_BF16>, hipFuncAttributeMaxDynamicSharedMemorySize, 131072);
    hipFuncSetAttribute((const void*)gemm256_k<128, EP_BIAS_RES>,  hipFuncAttributeMaxDynamicSharedMemorySize, 98304);
    hipFuncSetAttribute((const void*)gemm256_k<128, EP_BIAS_F32>,  hipFuncAttributeMaxDynamicSharedMemorySize, 98304);

    char* ws = (char*)d_ws;
    size_t off = 0;
    auto alloc = [&](size_t bytes) { size_t o = off; off += (bytes + 255) & ~(size_t)255; return o; };
    float* h    = (float*)(ws + alloc((size_t)MTOK * D_ * 4));
    bf16*  xn   = (bf16*) (ws + alloc((size_t)MTOK * D_ * 2));
    bf16*  abw  = (bf16*) (ws + alloc((size_t)L_ * 256 * D_ * 2));
    bf16*  outw = (bf16*) (ws + alloc((size_t)L_ * D_ * HN_ * 2));
    bf16*  wfw  = (bf16*) (ws + alloc((size_t)L_ * 2 * DFF_ * D_ * 2));  // w1|w3 interleaved [8192][1024]
    bf16*  w2w  = (bf16*) (ws + alloc((size_t)L_ * D_ * DFF_ * 2));
    bf16*  h1w  = (bf16*) (ws + alloc((size_t)2048 * D_ * 2));
    bf16*  h2w  = (bf16*) (ws + alloc((size_t)D_ * 2048 * 2));
    float* ab   = (float*)(ws + alloc((size_t)MTOK * 256 * 4));
    bf16*  hs   = (bf16*) (ws + alloc((size_t)MTOK * HN_ * 2));
    bf16*  c1   = (bf16*) (ws + alloc((size_t)MTOK * DFF_ * 2));  // also head g1

    auto T = [&](const float* src, bf16* dst, int K, int N, int rs, int ro) {
        transpose_k<<<dim3(N / 32, K / 32), dim3(32, 8), 0, stream>>>(src, dst, K, N, rs, ro);
    };

    for (int l = 0; l < L_; l++) {
        T(alpha_W + (size_t)l * D_ * HN_,  abw + (size_t)l * 256 * D_,                    D_,  HN_, 1, 0);
        T(in_W    + (size_t)l * D_ * HN_,  abw + (size_t)l * 256 * D_ + (size_t)HN_ * D_, D_,  HN_, 1, 0);
        T(out_W   + (size_t)l * HN_ * D_,  outw + (size_t)l * D_ * HN_,                   HN_, D_,  1, 0);
        T(w1_W    + (size_t)l * D_ * DFF_, wfw + (size_t)l * 2 * DFF_ * D_,               D_,  DFF_, 2, 0);
        T(w3_W    + (size_t)l * D_ * DFF_, wfw + (size_t)l * 2 * DFF_ * D_,               D_,  DFF_, 2, 1);
        T(w2_W    + (size_t)l * DFF_ * D_, w2w + (size_t)l * D_ * DFF_,                   DFF_, D_, 1, 0);
    }
    T(h1_W, h1w, D_, 2048, 1, 0);
    T(h2_W, h2w, 2048, D_, 1, 0);

    embed_k<<<MTOK, 256, 0, stream>>>(x, emb, pos_emb, h);

    for (int l = 0; l < L_; l++) {
        // ---- SSM block ----
        ln_k<<<MTOK, 256, 0, stream>>>(h, ssm_g + l * D_, ssm_be + l * D_, xn);
        gemm_k<EP_AB><<<dim3(64, 2), 256, 0, stream>>>(
            xn, abw + (size_t)l * 256 * D_, ab, nullptr,
            alpha_b + l * HN_, in_b + l * HN_, nullptr, nullptr, MTOK, 256, D_);
        ssm_scan_k<<<B_ * H_, 256, 0, stream>>>(ab, hs);
        gemm_k<EP_BIAS_RES><<<dim3(64, 8), 256, 0, stream>>>(
            hs, outw + (size_t)l * D_ * HN_, h, nullptr,
            out_b + l * D_, nullptr, h, nullptr, MTOK, D_, HN_);
        // ---- SwiGLU block: fused w1|w3 GEMM (N=8192 interleaved), then w2 ----
        ln_k<<<MTOK, 256, 0, stream>>>(h, ff_g + l * D_, ff_be + l * D_, xn);
        gemm256_k<256, EP_W13><<<dim3((MTOK / 256) * (2 * DFF_ / 256)), 512, 131072, stream>>>(
            xn, wfw + (size_t)l * 2 * DFF_ * D_, nullptr, c1,
            w1_b + l * DFF_, w3_b + l * DFF_, nullptr, nullptr, MTOK, 2 * DFF_, D_);
        gemm256_k<128, EP_BIAS_RES><<<dim3((MTOK / 256) * (D_ / 128)), 512, 98304, stream>>>(
            c1, w2w + (size_t)l * D_ * DFF_, h, nullptr,
            w2_b + l * D_, nullptr, h, nullptr, MTOK, D_, DFF_);
    }

    // ---- head ----
    ln_k<<<MTOK, 256, 0, stream>>>(h, on_g, on_be, xn);
    gemm256_k<256, EP_GELU_BF16><<<dim3((MTOK / 256) * (2048 / 256)), 512, 131072, stream>>>(
        xn, h1w, nullptr, c1, h1_b, nullptr, nullptr, nullptr, MTOK, 2048, D_);
    gemm256_k<128, EP_BIAS_F32><<<dim3((MTOK / 256) * (C_ / 128)), 512, 98304, stream>>>(
        c1, h2w, outp, nullptr, h2_b, nullptr, nullptr, nullptr, MTOK, C_, 2048);
}